// Round 8
// baseline (398.170 us; speedup 1.0000x reference)
//
#include <hip/hip_runtime.h>
#include <hip/hip_bf16.h>

// Gemma attention decode: B=32, L=1, HID=3072, H=16, KV=8, D=256, S=2048
// All fp32. Memory-bound: ~1.23 GB/call -> ~200us floor at 6.3 TB/s.
// R6 diag: attn=185us (~92% of its BW floor). R7: rest=127us vs ~37us model.
// R8 = DIAGNOSTIC #2: identical kernels to R7, but qkv/rope/oproj/finalize
// each launched TWICE (idempotent). rest_total = dur - 311.9us.

#define SCALE_ 0.0625f   // D^-0.5 = 1/16

// workspace layout (float offsets); ws ~2.1GB, we use 39MB
#define NKC   24u
#define OFF_XQKV (NKC*32u*8192u)           // 6291456
#define OFF_PO   (OFF_XQKV + 262144u)      // 6553600
#define OFF_ML   (1048576u)

__device__ inline void fma4(float4& a, float s, const float4& w) {
  a.x = fmaf(s, w.x, a.x); a.y = fmaf(s, w.y, a.y);
  a.z = fmaf(s, w.z, a.z); a.w = fmaf(s, w.w, a.w);
}
__device__ inline float dot4(const float4& a, const float4& b) {
  return a.x * b.x + a.y * b.y + a.z * b.z + a.w * b.w;
}
__device__ inline void scale_fma4(float4& a, float sc, float p, const float4& v) {
  a.x = fmaf(a.x, sc, p * v.x); a.y = fmaf(a.y, sc, p * v.y);
  a.z = fmaf(a.z, sc, p * v.z); a.w = fmaf(a.w, sc, p * v.w);
}

// ---------------------------------------------------------------------------
// Kernel A: QKV projection, split-K partials (unchanged from R7).
__global__ __launch_bounds__(256) void qkv_partial_kernel(
    const float* __restrict__ x, const float* __restrict__ wq,
    const float* __restrict__ wk, const float* __restrict__ wv,
    float* __restrict__ pqkv) {
  __shared__ float xls[32][128];            // 16 KB

  const int lane = threadIdx.x & 63;
  const int bg   = threadIdx.x >> 6;
  const int ctile = blockIdx.x & 31;
  const int kc    = blockIdx.x >> 5;
  const int n = ctile * 256 + lane * 4;

  for (int i = threadIdx.x; i < 1024; i += 256) {
    const int b = i >> 5;
    const int r = i & 31;
    *(float4*)(&xls[b][r * 4]) =
        *(const float4*)(x + (size_t)b * 3072 + kc * 128 + r * 4);
  }

  const float* w; int stride, nn;
  if (n < 4096)      { w = wq; stride = 4096; nn = n; }
  else if (n < 6144) { w = wk; stride = 2048; nn = n - 4096; }
  else               { w = wv; stride = 2048; nn = n - 6144; }
  const float* wb = w + (size_t)(kc * 128) * stride + nn;

  float4 acc[8];
#pragma unroll
  for (int j = 0; j < 8; ++j) acc[j] = make_float4(0.f, 0.f, 0.f, 0.f);

  __syncthreads();

  float4 wA[4], wB[4];
#define LDW(S, KK)                                                   \
  {                                                                  \
    S[0] = *(const float4*)(wb + (size_t)((KK) + 0) * stride);       \
    S[1] = *(const float4*)(wb + (size_t)((KK) + 1) * stride);       \
    S[2] = *(const float4*)(wb + (size_t)((KK) + 2) * stride);       \
    S[3] = *(const float4*)(wb + (size_t)((KK) + 3) * stride);       \
  }
#define CMP(S, KK)                                                   \
  {                                                                  \
    _Pragma("unroll")                                                \
    for (int j = 0; j < 8; ++j) {                                    \
      const float4 xv = *(const float4*)(&xls[bg * 8 + j][(KK)]);    \
      fma4(acc[j], xv.x, S[0]);                                      \
      fma4(acc[j], xv.y, S[1]);                                      \
      fma4(acc[j], xv.z, S[2]);                                      \
      fma4(acc[j], xv.w, S[3]);                                      \
    }                                                                \
  }

  LDW(wA, 0);
  for (int k = 0; k < 128; k += 8) {
    LDW(wB, k + 4);
    CMP(wA, k);
    const int kn = (k + 8 < 128) ? (k + 8) : 0;
    LDW(wA, kn);
    CMP(wB, k + 4);
  }
#undef LDW
#undef CMP

#pragma unroll
  for (int j = 0; j < 8; ++j) {
    *(float4*)(pqkv + ((size_t)kc * 32 + bg * 8 + j) * 8192 + n) = acc[j];
  }
}

// ---------------------------------------------------------------------------
// Kernel B: reduce 24 split-K partials + RoPE (unchanged from R7).
__global__ __launch_bounds__(256) void reduce_rope_kernel(
    const float* __restrict__ pqkv, const float* __restrict__ fcos,
    const float* __restrict__ fsin, float* __restrict__ xqkv) {
  const int w = blockIdx.x * 256 + threadIdx.x;   // < 40960
  const int b = w / 1280;
  const int r = w - b * 1280;
  const float* pb = pqkv + (size_t)b * 8192;
  float* ob = xqkv + (size_t)b * 8192;

  if (r < 768) {
    int n1, d;
    const bool isq = (r < 512);
    if (isq) { const int h = r >> 5; d = (r & 31) * 4; n1 = h * 256 + d; }
    else     { const int p = r - 512; const int kvh = p >> 5; d = (p & 31) * 4;
               n1 = 4096 + kvh * 256 + d; }
    const int n2 = n1 + 128;
    float4 xr = make_float4(0.f, 0.f, 0.f, 0.f);
    float4 xi = make_float4(0.f, 0.f, 0.f, 0.f);
    for (int kc = 0; kc < (int)NKC; ++kc) {
      const float4 a = *(const float4*)(pb + (size_t)kc * 262144 + n1);
      const float4 c = *(const float4*)(pb + (size_t)kc * 262144 + n2);
      xr.x += a.x; xr.y += a.y; xr.z += a.z; xr.w += a.w;
      xi.x += c.x; xi.y += c.y; xi.z += c.z; xi.w += c.w;
    }
    const float4 c = *(const float4*)(fcos + b * 128 + d);
    const float4 s = *(const float4*)(fsin + b * 128 + d);
    float4 o1, o2;
    o1.x = xr.x * c.x - xi.x * s.x;  o2.x = xr.x * s.x + xi.x * c.x;
    o1.y = xr.y * c.y - xi.y * s.y;  o2.y = xr.y * s.y + xi.y * c.y;
    o1.z = xr.z * c.z - xi.z * s.z;  o2.z = xr.z * s.z + xi.z * c.z;
    o1.w = xr.w * c.w - xi.w * s.w;  o2.w = xr.w * s.w + xi.w * c.w;
    if (isq) {
      o1.x *= SCALE_; o1.y *= SCALE_; o1.z *= SCALE_; o1.w *= SCALE_;
      o2.x *= SCALE_; o2.y *= SCALE_; o2.z *= SCALE_; o2.w *= SCALE_;
    }
    *(float4*)(ob + n1) = o1;
    *(float4*)(ob + n2) = o2;
  } else {
    const int nn = 6144 + (r - 768) * 4;
    float4 v = make_float4(0.f, 0.f, 0.f, 0.f);
    for (int kc = 0; kc < (int)NKC; ++kc) {
      const float4 a = *(const float4*)(pb + (size_t)kc * 262144 + nn);
      v.x += a.x; v.y += a.y; v.z += a.z; v.w += a.w;
    }
    *(float4*)(ob + nn) = v;
  }
}

// ---------------------------------------------------------------------------
// Kernel C: flash-decode attention chunk (unchanged; ~185us, 92% of floor).
__global__ __launch_bounds__(256) void attn_chunk_kernel(
    const float* __restrict__ xqkv, const float* __restrict__ cache_k,
    const float* __restrict__ cache_v, const float* __restrict__ mask,
    const int* __restrict__ posp, float* __restrict__ opart,
    float* __restrict__ ml) {
  __shared__ float accbuf[8][512];   // per stream: [g*256+d], 16 KB
  __shared__ float mred[8][4];       // per stream: m0,l0,m1,l1

  const int tid = threadIdx.x, lane = tid & 63, wv = tid >> 6;
  const int sub = lane & 31;
  const int stream = wv * 2 + (lane >> 5);   // 0..7
  const int c  = blockIdx.x & 7;
  const int kv = (blockIdx.x >> 3) & 7;
  const int b  = blockIdx.x >> 6;
  const int pos = posp[0];
  const int s0 = c * 256;
  const int dbase = sub * 8;

  const float* xb = xqkv + (size_t)b * 8192;
  const float* knew = xb + 4096 + kv * 256;
  const float* vnew = xb + 6144 + kv * 256;
  const size_t base = ((size_t)b * 8 + kv) * 2048 * 256;
  const float* kbase = cache_k + base;
  const float* vbase = cache_v + base;
  const float* mrow = mask + (size_t)b * 2048;

  const float4 qa0 = *(const float4*)(xb + (kv * 2 + 0) * 256 + dbase);
  const float4 qa1 = *(const float4*)(xb + (kv * 2 + 0) * 256 + dbase + 4);
  const float4 qb0 = *(const float4*)(xb + (kv * 2 + 1) * 256 + dbase);
  const float4 qb1 = *(const float4*)(xb + (kv * 2 + 1) * 256 + dbase + 4);

  float m0 = -3.4e38f, l0 = 0.f, m1 = -3.4e38f, l1 = 0.f;
  float4 a00 = make_float4(0.f, 0.f, 0.f, 0.f);
  float4 a01 = make_float4(0.f, 0.f, 0.f, 0.f);
  float4 a10 = make_float4(0.f, 0.f, 0.f, 0.f);
  float4 a11 = make_float4(0.f, 0.f, 0.f, 0.f);

  int sA = s0 + stream;
  int sB = sA + 8;
  const float* krA = (sA == pos) ? knew : (kbase + (size_t)sA * 256);
  const float* vrA = (sA == pos) ? vnew : (vbase + (size_t)sA * 256);
  const float* krB = (sB == pos) ? knew : (kbase + (size_t)sB * 256);
  const float* vrB = (sB == pos) ? vnew : (vbase + (size_t)sB * 256);
  float4 kA0 = *(const float4*)(krA + dbase);
  float4 kA1 = *(const float4*)(krA + dbase + 4);
  float4 vA0 = *(const float4*)(vrA + dbase);
  float4 vA1 = *(const float4*)(vrA + dbase + 4);
  float mkA = mrow[sA];
  float4 kB0 = *(const float4*)(krB + dbase);
  float4 kB1 = *(const float4*)(krB + dbase + 4);
  float4 vB0 = *(const float4*)(vrB + dbase);
  float4 vB1 = *(const float4*)(vrB + dbase + 4);
  float mkB = mrow[sB];

  for (int i = 0; i < 32; i += 2) {
    {
      float d0 = dot4(qa0, kA0) + dot4(qa1, kA1);
      float d1 = dot4(qb0, kA0) + dot4(qb1, kA1);
      const int ipf = (i + 2 < 32) ? (i + 2) : 31;
      const int sn = s0 + stream + 8 * ipf;
      const float* krn = (sn == pos) ? knew : (kbase + (size_t)sn * 256);
      const float* vrn = (sn == pos) ? vnew : (vbase + (size_t)sn * 256);
      kA0 = *(const float4*)(krn + dbase);
      kA1 = *(const float4*)(krn + dbase + 4);
      const float mkn = mrow[sn];
#pragma unroll
      for (int off = 16; off > 0; off >>= 1) {
        d0 += __shfl_xor(d0, off);
        d1 += __shfl_xor(d1, off);
      }
      d0 += mkA; d1 += mkA;
      const float nm0 = fmaxf(m0, d0);
      const float al0 = __expf(m0 - nm0);
      const float p0  = __expf(d0 - nm0);
      m0 = nm0; l0 = fmaf(l0, al0, p0);
      scale_fma4(a00, al0, p0, vA0);
      scale_fma4(a01, al0, p0, vA1);
      const float nm1 = fmaxf(m1, d1);
      const float al1 = __expf(m1 - nm1);
      const float p1  = __expf(d1 - nm1);
      m1 = nm1; l1 = fmaf(l1, al1, p1);
      scale_fma4(a10, al1, p1, vA0);
      scale_fma4(a11, al1, p1, vA1);
      vA0 = *(const float4*)(vrn + dbase);
      vA1 = *(const float4*)(vrn + dbase + 4);
      mkA = mkn;
    }
    {
      float d0 = dot4(qa0, kB0) + dot4(qa1, kB1);
      float d1 = dot4(qb0, kB0) + dot4(qb1, kB1);
      const int ipf = (i + 3 < 32) ? (i + 3) : 31;
      const int sn = s0 + stream + 8 * ipf;
      const float* krn = (sn == pos) ? knew : (kbase + (size_t)sn * 256);
      const float* vrn = (sn == pos) ? vnew : (vbase + (size_t)sn * 256);
      kB0 = *(const float4*)(krn + dbase);
      kB1 = *(const float4*)(krn + dbase + 4);
      const float mkn = mrow[sn];
#pragma unroll
      for (int off = 16; off > 0; off >>= 1) {
        d0 += __shfl_xor(d0, off);
        d1 += __shfl_xor(d1, off);
      }
      d0 += mkB; d1 += mkB;
      const float nm0 = fmaxf(m0, d0);
      const float al0 = __expf(m0 - nm0);
      const float p0  = __expf(d0 - nm0);
      m0 = nm0; l0 = fmaf(l0, al0, p0);
      scale_fma4(a00, al0, p0, vB0);
      scale_fma4(a01, al0, p0, vB1);
      const float nm1 = fmaxf(m1, d1);
      const float al1 = __expf(m1 - nm1);
      const float p1  = __expf(d1 - nm1);
      m1 = nm1; l1 = fmaf(l1, al1, p1);
      scale_fma4(a10, al1, p1, vB0);
      scale_fma4(a11, al1, p1, vB1);
      vB0 = *(const float4*)(vrn + dbase);
      vB1 = *(const float4*)(vrn + dbase + 4);
      mkB = mkn;
    }
  }

  if (sub == 0) {
    mred[stream][0] = m0; mred[stream][1] = l0;
    mred[stream][2] = m1; mred[stream][3] = l1;
  }
  __syncthreads();
  float M0 = -3.4e38f, M1 = -3.4e38f;
#pragma unroll
  for (int t = 0; t < 8; ++t) {
    M0 = fmaxf(M0, mred[t][0]);
    M1 = fmaxf(M1, mred[t][2]);
  }
  const float sc0 = __expf(m0 - M0);
  const float sc1 = __expf(m1 - M1);
  float* ab = &accbuf[stream][0];
  ab[dbase + 0] = a00.x * sc0; ab[dbase + 1] = a00.y * sc0;
  ab[dbase + 2] = a00.z * sc0; ab[dbase + 3] = a00.w * sc0;
  ab[dbase + 4] = a01.x * sc0; ab[dbase + 5] = a01.y * sc0;
  ab[dbase + 6] = a01.z * sc0; ab[dbase + 7] = a01.w * sc0;
  ab[256 + dbase + 0] = a10.x * sc1; ab[256 + dbase + 1] = a10.y * sc1;
  ab[256 + dbase + 2] = a10.z * sc1; ab[256 + dbase + 3] = a10.w * sc1;
  ab[256 + dbase + 4] = a11.x * sc1; ab[256 + dbase + 5] = a11.y * sc1;
  ab[256 + dbase + 6] = a11.z * sc1; ab[256 + dbase + 7] = a11.w * sc1;
  __syncthreads();

  if (tid == 0) {
    float L0 = 0.f, L1 = 0.f;
#pragma unroll
    for (int t = 0; t < 8; ++t) {
      L0 = fmaf(mred[t][1], __expf(mred[t][0] - M0), L0);
      L1 = fmaf(mred[t][3], __expf(mred[t][2] - M1), L1);
    }
    float2* mlp = (float2*)ml;
    const int mlbase = (((b * 8 + kv) * 8) + c) * 2;
    mlp[mlbase + 0] = make_float2(M0, L0);
    mlp[mlbase + 1] = make_float2(M1, L1);
  }

  const size_t obase = (size_t)((b * 8 + kv) * 8 + c) * 512;
  for (int t = tid; t < 512; t += 256) {
    float sum = 0.f;
#pragma unroll
    for (int st = 0; st < 8; ++st) sum += accbuf[st][t];
    opart[obase + t] = sum;
  }
}

// ---------------------------------------------------------------------------
// Kernel D: fused combine + output projection partials (unchanged from R7).
__global__ __launch_bounds__(256) void oproj_fused_kernel(
    const float* __restrict__ opart, const float* __restrict__ ml,
    const float* __restrict__ wo, float* __restrict__ po) {
  __shared__ float xs[32][128];   // 16 KB

  const int t = threadIdx.x;
  const int ctile = blockIdx.x % 24;
  const int rem   = blockIdx.x / 24;
  const int kc    = rem >> 1;            // head 0..15
  const int kh    = rem & 1;             // K-half 0..1 (128 dims)
  const int kvh = kc >> 1, g = kc & 1;

  {
    const int b = t >> 3;
    const int dloc = (t & 7) * 16;
    const int kvb = b * 8 + kvh;
    const float2* mlp = (const float2*)ml;
    float2 mls[8];
    float M = -3.4e38f;
#pragma unroll
    for (int c = 0; c < 8; ++c) {
      mls[c] = mlp[(kvb * 8 + c) * 2 + g];
      M = fmaxf(M, mls[c].x);
    }
    float L = 0.f;
    float4 O[4];
#pragma unroll
    for (int q = 0; q < 4; ++q) O[q] = make_float4(0.f, 0.f, 0.f, 0.f);
#pragma unroll
    for (int c = 0; c < 8; ++c) {
      const float wc = __expf(mls[c].x - M);
      L = fmaf(mls[c].y, wc, L);
      const float4* src = (const float4*)(opart +
          (size_t)(kvb * 8 + c) * 512 + g * 256 + kh * 128 + dloc);
#pragma unroll
      for (int q = 0; q < 4; ++q) fma4(O[q], wc, src[q]);
    }
    const float invL = 1.f / L;
    float4* dst = (float4*)(&xs[b][dloc]);
#pragma unroll
    for (int q = 0; q < 4; ++q) {
      dst[q] = make_float4(O[q].x * invL, O[q].y * invL,
                           O[q].z * invL, O[q].w * invL);
    }
  }
  __syncthreads();

  const int lane = t & 31;
  const int half = t >> 5;               // 0..7
  const int n = ctile * 128 + lane * 4;
  const float* wb = wo + (size_t)(kc * 256 + kh * 128) * 3072 + n;

  float4 acc[4];
#pragma unroll
  for (int j = 0; j < 4; ++j) acc[j] = make_float4(0.f, 0.f, 0.f, 0.f);

  float4 wA[4], wB[4];
#define LDW(S, KK)                                                 \
  {                                                                \
    S[0] = *(const float4*)(wb + (size_t)((KK) + 0) * 3072);       \
    S[1] = *(const float4*)(wb + (size_t)((KK) + 1) * 3072);       \
    S[2] = *(const float4*)(wb + (size_t)((KK) + 2) * 3072);       \
    S[3] = *(const float4*)(wb + (size_t)((KK) + 3) * 3072);       \
  }
#define CMP(S, KK)                                                 \
  {                                                                \
    _Pragma("unroll")                                              \
    for (int j = 0; j < 4; ++j) {                                  \
      const float4 xv = *(const float4*)(&xs[half * 4 + j][(KK)]); \
      fma4(acc[j], xv.x, S[0]);                                    \
      fma4(acc[j], xv.y, S[1]);                                    \
      fma4(acc[j], xv.z, S[2]);                                    \
      fma4(acc[j], xv.w, S[3]);                                    \
    }                                                              \
  }

  LDW(wA, 0);
  for (int k = 0; k < 128; k += 8) {
    LDW(wB, k + 4);
    CMP(wA, k);
    const int kn = (k + 8 < 128) ? (k + 8) : 0;
    LDW(wA, kn);
    CMP(wB, k + 4);
  }
#undef LDW
#undef CMP

#pragma unroll
  for (int j = 0; j < 4; ++j) {
    *(float4*)(po + ((size_t)(kc * 2 + kh) * 32 + half * 4 + j) * 3072 + n)
        = acc[j];
  }
}

// ---------------------------------------------------------------------------
// Kernel E: sum the 32 out-proj partials -> d_out (unchanged from R7).
__global__ __launch_bounds__(256) void finalize_kernel(
    const float* __restrict__ po, float* __restrict__ out) {
  const int i = blockIdx.x * 256 + threadIdx.x;  // < 24576 float4s
  const float4* p = (const float4*)po;
  float4 acc = make_float4(0.f, 0.f, 0.f, 0.f);
#pragma unroll
  for (int kc = 0; kc < 32; ++kc) {
    const float4 v = p[(size_t)kc * 24576 + i];
    acc.x += v.x; acc.y += v.y; acc.z += v.z; acc.w += v.w;
  }
  ((float4*)out)[i] = acc;
}

// ---------------------------------------------------------------------------
extern "C" void kernel_launch(void* const* d_in, const int* in_sizes, int n_in,
                              void* d_out, int out_size, void* d_ws, size_t ws_size,
                              hipStream_t stream) {
  (void)in_sizes; (void)n_in; (void)out_size; (void)ws_size;
  const float* x    = (const float*)d_in[0];
  const float* fcos = (const float*)d_in[1];
  const float* fsin = (const float*)d_in[2];
  const float* mask = (const float*)d_in[3];
  const float* ck   = (const float*)d_in[4];
  const float* cv   = (const float*)d_in[5];
  const float* wq   = (const float*)d_in[6];
  const float* wk   = (const float*)d_in[7];
  const float* wv   = (const float*)d_in[8];
  const float* wo   = (const float*)d_in[9];
  const int*   pos  = (const int*)d_in[10];

  float* ws    = (float*)d_ws;
  float* pqkv  = ws;                 // dead after reduce_rope
  float* opart = ws;                 // aliases pqkv (used after it's dead)
  float* ml    = ws + OFF_ML;
  float* xqkv  = ws + OFF_XQKV;
  float* po    = ws + OFF_PO;
  float* out   = (float*)d_out;

  // DIAGNOSTIC: all small kernels doubled (idempotent). attn single.
  // rest_total = dur - 311.9us.
  qkv_partial_kernel<<<768, 256, 0, stream>>>(x, wq, wk, wv, pqkv);
  qkv_partial_kernel<<<768, 256, 0, stream>>>(x, wq, wk, wv, pqkv);
  reduce_rope_kernel<<<160, 256, 0, stream>>>(pqkv, fcos, fsin, xqkv);
  reduce_rope_kernel<<<160, 256, 0, stream>>>(pqkv, fcos, fsin, xqkv);
  attn_chunk_kernel<<<2048, 256, 0, stream>>>(xqkv, ck, cv, mask, pos, opart, ml);
  oproj_fused_kernel<<<768, 256, 0, stream>>>(opart, ml, wo, po);
  oproj_fused_kernel<<<768, 256, 0, stream>>>(opart, ml, wo, po);
  finalize_kernel<<<96, 256, 0, stream>>>(po, out);
  finalize_kernel<<<96, 256, 0, stream>>>(po, out);
}

// Round 9
// 304.767 us; speedup vs baseline: 1.3065x; 1.3065x over previous
//
#include <hip/hip_runtime.h>
#include <hip/hip_bf16.h>

// Gemma attention decode: B=32, L=1, HID=3072, H=16, KV=8, D=256, S=2048
// All fp32. Memory-bound. Measured: attn=185us (92% of floor); rest=127 cold.
// R9: non-temporal hints on all single-use streams (weights, K/V, partials).

#define SCALE_ 0.0625f   // D^-0.5 = 1/16

#define NKC   24u
#define OFF_XQKV (NKC*32u*8192u)           // 6291456
#define OFF_PO   (OFF_XQKV + 262144u)      // 6553600
#define OFF_ML   (1048576u)

typedef float f32x4 __attribute__((ext_vector_type(4)));

__device__ inline f32x4 ntl4(const float* p) {
  return __builtin_nontemporal_load((const f32x4*)p);
}
__device__ inline void nts4(float* p, f32x4 v) {
  __builtin_nontemporal_store(v, (f32x4*)p);
}
__device__ inline f32x4 ld4(const float* p) { return *(const f32x4*)p; }

__device__ inline void fma4(float4& a, float s, const float4& w) {
  a.x = fmaf(s, w.x, a.x); a.y = fmaf(s, w.y, a.y);
  a.z = fmaf(s, w.z, a.z); a.w = fmaf(s, w.w, a.w);
}
__device__ inline float dot4v(f32x4 a, f32x4 b) {
  return a.x * b.x + a.y * b.y + a.z * b.z + a.w * b.w;
}

// ---------------------------------------------------------------------------
// Kernel A: QKV projection, split-K partials. grid = 32 ctiles x 24 K-chunks.
// Weights: NT loads (single-use). pqkv: NT stores (cross-XCD anyway).
__global__ __launch_bounds__(256) void qkv_partial_kernel(
    const float* __restrict__ x, const float* __restrict__ wq,
    const float* __restrict__ wk, const float* __restrict__ wv,
    float* __restrict__ pqkv) {
  __shared__ float xls[32][128];            // 16 KB

  const int lane = threadIdx.x & 63;
  const int bg   = threadIdx.x >> 6;        // 0..3 -> batches bg*8..bg*8+7
  const int ctile = blockIdx.x & 31;
  const int kc    = blockIdx.x >> 5;        // 0..23
  const int n = ctile * 256 + lane * 4;

  for (int i = threadIdx.x; i < 1024; i += 256) {
    const int b = i >> 5;
    const int r = i & 31;
    *(f32x4*)(&xls[b][r * 4]) = ld4(x + (size_t)b * 3072 + kc * 128 + r * 4);
  }

  const float* w; int stride, nn;
  if (n < 4096)      { w = wq; stride = 4096; nn = n; }
  else if (n < 6144) { w = wk; stride = 2048; nn = n - 4096; }
  else               { w = wv; stride = 2048; nn = n - 6144; }
  const float* wb = w + (size_t)(kc * 128) * stride + nn;

  f32x4 acc[8];
#pragma unroll
  for (int j = 0; j < 8; ++j) acc[j] = (f32x4){0.f, 0.f, 0.f, 0.f};

  __syncthreads();

  f32x4 wA[4], wB[4];
#define LDW(S, KK)                                                   \
  {                                                                  \
    S[0] = ntl4(wb + (size_t)((KK) + 0) * stride);                   \
    S[1] = ntl4(wb + (size_t)((KK) + 1) * stride);                   \
    S[2] = ntl4(wb + (size_t)((KK) + 2) * stride);                   \
    S[3] = ntl4(wb + (size_t)((KK) + 3) * stride);                   \
  }
#define CMP(S, KK)                                                   \
  {                                                                  \
    _Pragma("unroll")                                                \
    for (int j = 0; j < 8; ++j) {                                    \
      const f32x4 xv = *(const f32x4*)(&xls[bg * 8 + j][(KK)]);      \
      acc[j] += xv.x * S[0];                                         \
      acc[j] += xv.y * S[1];                                         \
      acc[j] += xv.z * S[2];                                         \
      acc[j] += xv.w * S[3];                                         \
    }                                                                \
  }

  LDW(wA, 0);
  for (int k = 0; k < 128; k += 8) {
    LDW(wB, k + 4);
    CMP(wA, k);
    const int kn = (k + 8 < 128) ? (k + 8) : 0;
    LDW(wA, kn);
    CMP(wB, k + 4);
  }
#undef LDW
#undef CMP

#pragma unroll
  for (int j = 0; j < 8; ++j) {
    nts4(pqkv + ((size_t)kc * 32 + bg * 8 + j) * 8192 + n, acc[j]);
  }
}

// ---------------------------------------------------------------------------
// Kernel B: reduce 24 split-K partials + RoPE. pqkv: NT loads (single-use).
// xqkv write stays cached (attn re-reads it from every block).
__global__ __launch_bounds__(256) void reduce_rope_kernel(
    const float* __restrict__ pqkv, const float* __restrict__ fcos,
    const float* __restrict__ fsin, float* __restrict__ xqkv) {
  const int w = blockIdx.x * 256 + threadIdx.x;   // < 40960
  const int b = w / 1280;
  const int r = w - b * 1280;
  const float* pb = pqkv + (size_t)b * 8192;
  float* ob = xqkv + (size_t)b * 8192;

  if (r < 768) {
    int n1, d;
    const bool isq = (r < 512);
    if (isq) { const int h = r >> 5; d = (r & 31) * 4; n1 = h * 256 + d; }
    else     { const int p = r - 512; const int kvh = p >> 5; d = (p & 31) * 4;
               n1 = 4096 + kvh * 256 + d; }
    const int n2 = n1 + 128;
    f32x4 xr = (f32x4){0.f, 0.f, 0.f, 0.f};
    f32x4 xi = (f32x4){0.f, 0.f, 0.f, 0.f};
    for (int kc = 0; kc < (int)NKC; ++kc) {
      xr += ntl4(pb + (size_t)kc * 262144 + n1);
      xi += ntl4(pb + (size_t)kc * 262144 + n2);
    }
    const f32x4 c = ld4(fcos + b * 128 + d);
    const f32x4 s = ld4(fsin + b * 128 + d);
    f32x4 o1 = xr * c - xi * s;
    f32x4 o2 = xr * s + xi * c;
    if (isq) { o1 *= SCALE_; o2 *= SCALE_; }
    *(f32x4*)(ob + n1) = o1;
    *(f32x4*)(ob + n2) = o2;
  } else {
    const int nn = 6144 + (r - 768) * 4;
    f32x4 v = (f32x4){0.f, 0.f, 0.f, 0.f};
    for (int kc = 0; kc < (int)NKC; ++kc) {
      v += ntl4(pb + (size_t)kc * 262144 + nn);
    }
    *(f32x4*)(ob + nn) = v;
  }
}

// ---------------------------------------------------------------------------
// Kernel C: flash-decode attention chunk. K/V: NT loads (pure stream).
__global__ __launch_bounds__(256) void attn_chunk_kernel(
    const float* __restrict__ xqkv, const float* __restrict__ cache_k,
    const float* __restrict__ cache_v, const float* __restrict__ mask,
    const int* __restrict__ posp, float* __restrict__ opart,
    float* __restrict__ ml) {
  __shared__ float accbuf[8][512];   // per stream: [g*256+d], 16 KB
  __shared__ float mred[8][4];       // per stream: m0,l0,m1,l1

  const int tid = threadIdx.x, lane = tid & 63, wv = tid >> 6;
  const int sub = lane & 31;
  const int stream = wv * 2 + (lane >> 5);   // 0..7
  const int c  = blockIdx.x & 7;
  const int kv = (blockIdx.x >> 3) & 7;
  const int b  = blockIdx.x >> 6;
  const int pos = posp[0];
  const int s0 = c * 256;
  const int dbase = sub * 8;

  const float* xb = xqkv + (size_t)b * 8192;
  const float* knew = xb + 4096 + kv * 256;
  const float* vnew = xb + 6144 + kv * 256;
  const size_t base = ((size_t)b * 8 + kv) * 2048 * 256;
  const float* kbase = cache_k + base;
  const float* vbase = cache_v + base;
  const float* mrow = mask + (size_t)b * 2048;

  const f32x4 qa0 = ld4(xb + (kv * 2 + 0) * 256 + dbase);
  const f32x4 qa1 = ld4(xb + (kv * 2 + 0) * 256 + dbase + 4);
  const f32x4 qb0 = ld4(xb + (kv * 2 + 1) * 256 + dbase);
  const f32x4 qb1 = ld4(xb + (kv * 2 + 1) * 256 + dbase + 4);

  float m0 = -3.4e38f, l0 = 0.f, m1 = -3.4e38f, l1 = 0.f;
  f32x4 a00 = (f32x4){0.f, 0.f, 0.f, 0.f};
  f32x4 a01 = (f32x4){0.f, 0.f, 0.f, 0.f};
  f32x4 a10 = (f32x4){0.f, 0.f, 0.f, 0.f};
  f32x4 a11 = (f32x4){0.f, 0.f, 0.f, 0.f};

  int sA = s0 + stream;
  int sB = sA + 8;
  const float* krA = (sA == pos) ? knew : (kbase + (size_t)sA * 256);
  const float* vrA = (sA == pos) ? vnew : (vbase + (size_t)sA * 256);
  const float* krB = (sB == pos) ? knew : (kbase + (size_t)sB * 256);
  const float* vrB = (sB == pos) ? vnew : (vbase + (size_t)sB * 256);
  f32x4 kA0 = ntl4(krA + dbase);
  f32x4 kA1 = ntl4(krA + dbase + 4);
  f32x4 vA0 = ntl4(vrA + dbase);
  f32x4 vA1 = ntl4(vrA + dbase + 4);
  float mkA = mrow[sA];
  f32x4 kB0 = ntl4(krB + dbase);
  f32x4 kB1 = ntl4(krB + dbase + 4);
  f32x4 vB0 = ntl4(vrB + dbase);
  f32x4 vB1 = ntl4(vrB + dbase + 4);
  float mkB = mrow[sB];

  for (int i = 0; i < 32; i += 2) {
    {
      float d0 = dot4v(qa0, kA0) + dot4v(qa1, kA1);
      float d1 = dot4v(qb0, kA0) + dot4v(qb1, kA1);
      const int ipf = (i + 2 < 32) ? (i + 2) : 31;
      const int sn = s0 + stream + 8 * ipf;
      const float* krn = (sn == pos) ? knew : (kbase + (size_t)sn * 256);
      const float* vrn = (sn == pos) ? vnew : (vbase + (size_t)sn * 256);
      kA0 = ntl4(krn + dbase);
      kA1 = ntl4(krn + dbase + 4);
      const float mkn = mrow[sn];
#pragma unroll
      for (int off = 16; off > 0; off >>= 1) {
        d0 += __shfl_xor(d0, off);
        d1 += __shfl_xor(d1, off);
      }
      d0 += mkA; d1 += mkA;
      const float nm0 = fmaxf(m0, d0);
      const float al0 = __expf(m0 - nm0);
      const float p0  = __expf(d0 - nm0);
      m0 = nm0; l0 = fmaf(l0, al0, p0);
      a00 = a00 * al0 + p0 * vA0;
      a01 = a01 * al0 + p0 * vA1;
      const float nm1 = fmaxf(m1, d1);
      const float al1 = __expf(m1 - nm1);
      const float p1  = __expf(d1 - nm1);
      m1 = nm1; l1 = fmaf(l1, al1, p1);
      a10 = a10 * al1 + p1 * vA0;
      a11 = a11 * al1 + p1 * vA1;
      vA0 = ntl4(vrn + dbase);
      vA1 = ntl4(vrn + dbase + 4);
      mkA = mkn;
    }
    {
      float d0 = dot4v(qa0, kB0) + dot4v(qa1, kB1);
      float d1 = dot4v(qb0, kB0) + dot4v(qb1, kB1);
      const int ipf = (i + 3 < 32) ? (i + 3) : 31;
      const int sn = s0 + stream + 8 * ipf;
      const float* krn = (sn == pos) ? knew : (kbase + (size_t)sn * 256);
      const float* vrn = (sn == pos) ? vnew : (vbase + (size_t)sn * 256);
      kB0 = ntl4(krn + dbase);
      kB1 = ntl4(krn + dbase + 4);
      const float mkn = mrow[sn];
#pragma unroll
      for (int off = 16; off > 0; off >>= 1) {
        d0 += __shfl_xor(d0, off);
        d1 += __shfl_xor(d1, off);
      }
      d0 += mkB; d1 += mkB;
      const float nm0 = fmaxf(m0, d0);
      const float al0 = __expf(m0 - nm0);
      const float p0  = __expf(d0 - nm0);
      m0 = nm0; l0 = fmaf(l0, al0, p0);
      a00 = a00 * al0 + p0 * vB0;
      a01 = a01 * al0 + p0 * vB1;
      const float nm1 = fmaxf(m1, d1);
      const float al1 = __expf(m1 - nm1);
      const float p1  = __expf(d1 - nm1);
      m1 = nm1; l1 = fmaf(l1, al1, p1);
      a10 = a10 * al1 + p1 * vB0;
      a11 = a11 * al1 + p1 * vB1;
      vB0 = ntl4(vrn + dbase);
      vB1 = ntl4(vrn + dbase + 4);
      mkB = mkn;
    }
  }

  if (sub == 0) {
    mred[stream][0] = m0; mred[stream][1] = l0;
    mred[stream][2] = m1; mred[stream][3] = l1;
  }
  __syncthreads();
  float M0 = -3.4e38f, M1 = -3.4e38f;
#pragma unroll
  for (int t = 0; t < 8; ++t) {
    M0 = fmaxf(M0, mred[t][0]);
    M1 = fmaxf(M1, mred[t][2]);
  }
  const float sc0 = __expf(m0 - M0);
  const float sc1 = __expf(m1 - M1);
  float* ab = &accbuf[stream][0];
  ab[dbase + 0] = a00.x * sc0; ab[dbase + 1] = a00.y * sc0;
  ab[dbase + 2] = a00.z * sc0; ab[dbase + 3] = a00.w * sc0;
  ab[dbase + 4] = a01.x * sc0; ab[dbase + 5] = a01.y * sc0;
  ab[dbase + 6] = a01.z * sc0; ab[dbase + 7] = a01.w * sc0;
  ab[256 + dbase + 0] = a10.x * sc1; ab[256 + dbase + 1] = a10.y * sc1;
  ab[256 + dbase + 2] = a10.z * sc1; ab[256 + dbase + 3] = a10.w * sc1;
  ab[256 + dbase + 4] = a11.x * sc1; ab[256 + dbase + 5] = a11.y * sc1;
  ab[256 + dbase + 6] = a11.z * sc1; ab[256 + dbase + 7] = a11.w * sc1;
  __syncthreads();

  if (tid == 0) {
    float L0 = 0.f, L1 = 0.f;
#pragma unroll
    for (int t = 0; t < 8; ++t) {
      L0 = fmaf(mred[t][1], __expf(mred[t][0] - M0), L0);
      L1 = fmaf(mred[t][3], __expf(mred[t][2] - M1), L1);
    }
    float2* mlp = (float2*)ml;
    const int mlbase = (((b * 8 + kv) * 8) + c) * 2;
    mlp[mlbase + 0] = make_float2(M0, L0);
    mlp[mlbase + 1] = make_float2(M1, L1);
  }

  const size_t obase = (size_t)((b * 8 + kv) * 8 + c) * 512;
  for (int t = tid; t < 512; t += 256) {
    float sum = 0.f;
#pragma unroll
    for (int st = 0; st < 8; ++st) sum += accbuf[st][t];
    opart[obase + t] = sum;     // cached: oproj re-reads heavily
  }
}

// ---------------------------------------------------------------------------
// Kernel D: fused combine + output projection partials. wo: NT loads.
__global__ __launch_bounds__(256) void oproj_fused_kernel(
    const float* __restrict__ opart, const float* __restrict__ ml,
    const float* __restrict__ wo, float* __restrict__ po) {
  __shared__ float xs[32][128];   // 16 KB

  const int t = threadIdx.x;
  const int ctile = blockIdx.x % 24;
  const int rem   = blockIdx.x / 24;
  const int kc    = rem >> 1;            // head 0..15
  const int kh    = rem & 1;             // K-half 0..1 (128 dims)
  const int kvh = kc >> 1, g = kc & 1;

  {
    const int b = t >> 3;
    const int dloc = (t & 7) * 16;
    const int kvb = b * 8 + kvh;
    const float2* mlp = (const float2*)ml;
    float2 mls[8];
    float M = -3.4e38f;
#pragma unroll
    for (int c = 0; c < 8; ++c) {
      mls[c] = mlp[(kvb * 8 + c) * 2 + g];
      M = fmaxf(M, mls[c].x);
    }
    float L = 0.f;
    f32x4 O[4];
#pragma unroll
    for (int q = 0; q < 4; ++q) O[q] = (f32x4){0.f, 0.f, 0.f, 0.f};
#pragma unroll
    for (int c = 0; c < 8; ++c) {
      const float wc = __expf(mls[c].x - M);
      L = fmaf(mls[c].y, wc, L);
      const float* src = opart +
          (size_t)(kvb * 8 + c) * 512 + g * 256 + kh * 128 + dloc;
#pragma unroll
      for (int q = 0; q < 4; ++q) O[q] += wc * ld4(src + q * 4);
    }
    const float invL = 1.f / L;
#pragma unroll
    for (int q = 0; q < 4; ++q) {
      *(f32x4*)(&xs[b][dloc + q * 4]) = O[q] * invL;
    }
  }
  __syncthreads();

  const int lane = t & 31;
  const int half = t >> 5;               // 0..7
  const int n = ctile * 128 + lane * 4;
  const float* wb = wo + (size_t)(kc * 256 + kh * 128) * 3072 + n;

  f32x4 acc[4];
#pragma unroll
  for (int j = 0; j < 4; ++j) acc[j] = (f32x4){0.f, 0.f, 0.f, 0.f};

  f32x4 wA[4], wB[4];
#define LDW(S, KK)                                                 \
  {                                                                \
    S[0] = ntl4(wb + (size_t)((KK) + 0) * 3072);                   \
    S[1] = ntl4(wb + (size_t)((KK) + 1) * 3072);                   \
    S[2] = ntl4(wb + (size_t)((KK) + 2) * 3072);                   \
    S[3] = ntl4(wb + (size_t)((KK) + 3) * 3072);                   \
  }
#define CMP(S, KK)                                                 \
  {                                                                \
    _Pragma("unroll")                                              \
    for (int j = 0; j < 4; ++j) {                                  \
      const f32x4 xv = *(const f32x4*)(&xs[half * 4 + j][(KK)]);   \
      acc[j] += xv.x * S[0];                                       \
      acc[j] += xv.y * S[1];                                       \
      acc[j] += xv.z * S[2];                                       \
      acc[j] += xv.w * S[3];                                       \
    }                                                              \
  }

  LDW(wA, 0);
  for (int k = 0; k < 128; k += 8) {
    LDW(wB, k + 4);
    CMP(wA, k);
    const int kn = (k + 8 < 128) ? (k + 8) : 0;
    LDW(wA, kn);
    CMP(wB, k + 4);
  }
#undef LDW
#undef CMP

#pragma unroll
  for (int j = 0; j < 4; ++j) {
    *(f32x4*)(po + ((size_t)(kc * 2 + kh) * 32 + half * 4 + j) * 3072 + n)
        = acc[j];
  }
}

// ---------------------------------------------------------------------------
// Kernel E: sum the 32 out-proj partials -> d_out. po: NT loads.
__global__ __launch_bounds__(256) void finalize_kernel(
    const float* __restrict__ po, float* __restrict__ out) {
  const int i = blockIdx.x * 256 + threadIdx.x;  // < 24576 float4s
  f32x4 acc = (f32x4){0.f, 0.f, 0.f, 0.f};
#pragma unroll
  for (int kc = 0; kc < 32; ++kc) {
    acc += ntl4(po + ((size_t)kc * 24576 + i) * 4);
  }
  *(f32x4*)((float*)out + (size_t)i * 4) = acc;
}

// ---------------------------------------------------------------------------
extern "C" void kernel_launch(void* const* d_in, const int* in_sizes, int n_in,
                              void* d_out, int out_size, void* d_ws, size_t ws_size,
                              hipStream_t stream) {
  (void)in_sizes; (void)n_in; (void)out_size; (void)ws_size;
  const float* x    = (const float*)d_in[0];
  const float* fcos = (const float*)d_in[1];
  const float* fsin = (const float*)d_in[2];
  const float* mask = (const float*)d_in[3];
  const float* ck   = (const float*)d_in[4];
  const float* cv   = (const float*)d_in[5];
  const float* wq   = (const float*)d_in[6];
  const float* wk   = (const float*)d_in[7];
  const float* wv   = (const float*)d_in[8];
  const float* wo   = (const float*)d_in[9];
  const int*   pos  = (const int*)d_in[10];

  float* ws    = (float*)d_ws;
  float* pqkv  = ws;                 // dead after reduce_rope
  float* opart = ws;                 // aliases pqkv (used after it's dead)
  float* ml    = ws + OFF_ML;
  float* xqkv  = ws + OFF_XQKV;
  float* po    = ws + OFF_PO;
  float* out   = (float*)d_out;

  qkv_partial_kernel<<<768, 256, 0, stream>>>(x, wq, wk, wv, pqkv);
  reduce_rope_kernel<<<160, 256, 0, stream>>>(pqkv, fcos, fsin, xqkv);
  attn_chunk_kernel<<<2048, 256, 0, stream>>>(xqkv, ck, cv, mask, pos, opart, ml);
  oproj_fused_kernel<<<768, 256, 0, stream>>>(opart, ml, wo, po);
  finalize_kernel<<<96, 256, 0, stream>>>(po, out);
}